// Round 4
// baseline (9797.897 us; speedup 1.0000x reference)
//
#include <hip/hip_runtime.h>
#include <hip/hip_fp16.h>
#include <math.h>

#define T_LEN 2500
#define BATCH 64
#define CH    12
#define HID   64
#define G4    256   // 4*H
#define D2    128   // 2*H
#define NROW  (T_LEN*BATCH)

typedef __attribute__((ext_vector_type(2))) float f32x2;
typedef __attribute__((ext_vector_type(4))) float f32x4;

__device__ __forceinline__ float rcp_(float x){ return __builtin_amdgcn_rcpf(x); }
__device__ __forceinline__ float sig_(float x){ return rcp_(1.f + __expf(-x)); }
__device__ __forceinline__ float tanh_(float x){ return fmaf(-2.f, rcp_(1.f + __expf(2.f*x)), 1.f); }

__device__ __forceinline__ float ldv(const float* p){ return *p; }
__device__ __forceinline__ float ldv(const __half* p){ return __half2float(*p); }
__device__ __forceinline__ void stv(float* p, float v){ *p = v; }
__device__ __forceinline__ void stv(__half* p, float v){ *p = __float2half(v); }

// VOP3P packed fma, h broadcast from a half of the pair operand.
// d.lo += h.lo*w.lo ; d.hi += h.lo*w.hi
__device__ __forceinline__ void pkfma_lo(f32x2& d, f32x2 h, f32x2 w) {
  asm("v_pk_fma_f32 %0, %1, %2, %0 op_sel:[0,0,0] op_sel_hi:[0,1,1]"
      : "+v"(d) : "v"(h), "v"(w));
}
// d.lo += h.hi*w.lo ; d.hi += h.hi*w.hi
__device__ __forceinline__ void pkfma_hi(f32x2& d, f32x2 h, f32x2 w) {
  asm("v_pk_fma_f32 %0, %1, %2, %0 op_sel:[1,0,0] op_sel_hi:[1,1,1]"
      : "+v"(d) : "v"(h), "v"(w));
}

// Full hh GEMV step: acc pairs (i,f) and (g,o) over K=64 from LDS h.
__device__ __forceinline__ void hh_pk(const float* h_lds, const f32x2* w_if, const f32x2* w_go,
                                      f32x2& aif0, f32x2& aif1, f32x2& ago0, f32x2& ago1) {
#pragma unroll
  for (int k = 0; k < HID; k += 4) {
    const f32x4 h4 = *reinterpret_cast<const f32x4*>(&h_lds[k]);
    const f32x2 ha = __builtin_shufflevector(h4, h4, 0, 1);
    const f32x2 hb = __builtin_shufflevector(h4, h4, 2, 3);
    pkfma_lo(aif0, ha, w_if[k]);     pkfma_lo(ago0, ha, w_go[k]);
    pkfma_hi(aif1, ha, w_if[k + 1]); pkfma_hi(ago1, ha, w_go[k + 1]);
    pkfma_lo(aif0, hb, w_if[k + 2]); pkfma_lo(ago0, hb, w_go[k + 2]);
    pkfma_hi(aif1, hb, w_if[k + 3]); pkfma_hi(ago1, hb, w_go[k + 3]);
  }
}

// ---------------------------------------------------------------------------
// Fold input projection into layer-0 input weights.
// ---------------------------------------------------------------------------
__global__ void k_prep0(const float* __restrict__ Wp, const float* __restrict__ bp,
                        const float* __restrict__ w_ih0,
                        const float* __restrict__ b_ih0, const float* __restrict__ b_hh0,
                        float* __restrict__ w0p, float* __restrict__ b0p) {
  int tid = blockIdx.x * blockDim.x + threadIdx.x;
  if (tid >= 2 * G4) return;
  const float* wih = w_ih0 + (size_t)tid * HID;
  float bb = b_ih0[tid] + b_hh0[tid];
  for (int j = 0; j < HID; ++j) bb += wih[j] * bp[j];
  b0p[tid] = bb;
  for (int c = 0; c < CH; ++c) {
    float s = 0.f;
    for (int j = 0; j < HID; ++j) s += wih[j] * Wp[j * CH + c];
    w0p[(size_t)tid * CH + c] = s;
  }
}

// ---------------------------------------------------------------------------
// Layer-0 recurrence: single wave per (dir,b). Lane j owns hidden unit j.
// Whh packed in 256 VGPRs as (i,f)/(g,o) pairs; h broadcast via pk op_sel.
// No barriers in the time loop.
// ---------------------------------------------------------------------------
template<typename ST>
__global__ __launch_bounds__(64) void k_recur0(const float* __restrict__ x,
                                               const float* __restrict__ w0p,
                                               const float* __restrict__ b0p,
                                               const float* __restrict__ whh,
                                               ST* __restrict__ seq) {
  const int wg = blockIdx.x, dir = wg >> 6, b = wg & 63, j = threadIdx.x;

  f32x2 w_if[HID], w_go[HID];
  {
    const float* Wi = whh + ((size_t)dir * G4 + 0 * HID + j) * HID;
    const float* Wf = whh + ((size_t)dir * G4 + 1 * HID + j) * HID;
    const float* Wg = whh + ((size_t)dir * G4 + 2 * HID + j) * HID;
    const float* Wo = whh + ((size_t)dir * G4 + 3 * HID + j) * HID;
#pragma unroll
    for (int k = 0; k < HID; ++k) {
      w_if[k] = f32x2{Wi[k], Wf[k]};
      w_go[k] = f32x2{Wg[k], Wo[k]};
    }
  }
  float w0i[CH], w0f[CH], w0g[CH], w0o[CH];
  {
    const float* Pi = w0p + ((size_t)dir * G4 + 0 * HID + j) * CH;
    const float* Pf = w0p + ((size_t)dir * G4 + 1 * HID + j) * CH;
    const float* Pg = w0p + ((size_t)dir * G4 + 2 * HID + j) * CH;
    const float* Po = w0p + ((size_t)dir * G4 + 3 * HID + j) * CH;
#pragma unroll
    for (int c = 0; c < CH; ++c) { w0i[c] = Pi[c]; w0f[c] = Pf[c]; w0g[c] = Pg[c]; w0o[c] = Po[c]; }
  }
  const float bi = b0p[dir * G4 + j],           bf = b0p[dir * G4 + HID + j];
  const float bg = b0p[dir * G4 + 2 * HID + j], bo = b0p[dir * G4 + 3 * HID + j];

  __shared__ __align__(16) float h_lds[HID];
  h_lds[j] = 0.f;
  float c = 0.f;
  __syncthreads();

  int t = dir ? (T_LEN - 1) : 0;
  const int dt = dir ? -1 : 1;
  const float* xb = x + (size_t)b * CH * T_LEN;

  float xc[CH], xn[CH];
#pragma unroll
  for (int cc = 0; cc < CH; ++cc) xc[cc] = xb[(size_t)cc * T_LEN + t];

  for (int it = 0; it < T_LEN; ++it) {
    const int tn = t + dt;
    const int tcl = (tn < 0) ? 0 : ((tn > T_LEN - 1) ? (T_LEN - 1) : tn);
#pragma unroll
    for (int cc = 0; cc < CH; ++cc) xn[cc] = xb[(size_t)cc * T_LEN + tcl];

    // input projection: 4 scalar accumulators
    float pi = bi, pf = bf, pg = bg, po = bo;
#pragma unroll
    for (int cc = 0; cc < CH; ++cc) {
      pi = fmaf(xc[cc], w0i[cc], pi);
      pf = fmaf(xc[cc], w0f[cc], pf);
      pg = fmaf(xc[cc], w0g[cc], pg);
      po = fmaf(xc[cc], w0o[cc], po);
    }
    f32x2 aif0 = f32x2{pi, pf}, ago0 = f32x2{pg, po};
    f32x2 aif1 = f32x2{0.f, 0.f}, ago1 = f32x2{0.f, 0.f};
    hh_pk(h_lds, w_if, w_go, aif0, aif1, ago0, ago1);
    const f32x2 pif = aif0 + aif1;
    const f32x2 pgo = ago0 + ago1;

    const float i_ = sig_(pif.x), f_ = sig_(pif.y);
    const float g_ = tanh_(pgo.x), o_ = sig_(pgo.y);
    c = fmaf(f_, c, i_ * g_);
    const float hv = o_ * tanh_(c);
    h_lds[j] = hv;
    stv(&seq[((size_t)t * BATCH + b) * D2 + dir * HID + j], hv);

#pragma unroll
    for (int cc = 0; cc < CH; ++cc) xc[cc] = xn[cc];
    t = tn;
  }
}

// ---------------------------------------------------------------------------
// Layers 1/2 recurrence over one time-chunk (xw precomputed, bias folded in).
// Single wave per (dir,b); h/c carried across chunks in hst/cst.
// ---------------------------------------------------------------------------
template<typename ST>
__global__ __launch_bounds__(64) void k_recur12(const float* __restrict__ xwF,
                                                const float* __restrict__ xwB,
                                                const float* __restrict__ whh,
                                                ST* __restrict__ seq,
                                                float* __restrict__ hst, float* __restrict__ cst,
                                                int initFlag, int tF0, int tB0, int TC) {
  const int wg = blockIdx.x, dir = wg >> 6, b = wg & 63, j = threadIdx.x;
  const float* xw = dir ? xwB : xwF;

  f32x2 w_if[HID], w_go[HID];
  {
    const float* Wi = whh + ((size_t)dir * G4 + 0 * HID + j) * HID;
    const float* Wf = whh + ((size_t)dir * G4 + 1 * HID + j) * HID;
    const float* Wg = whh + ((size_t)dir * G4 + 2 * HID + j) * HID;
    const float* Wo = whh + ((size_t)dir * G4 + 3 * HID + j) * HID;
#pragma unroll
    for (int k = 0; k < HID; ++k) {
      w_if[k] = f32x2{Wi[k], Wf[k]};
      w_go[k] = f32x2{Wg[k], Wo[k]};
    }
  }

  __shared__ __align__(16) float h_lds[HID];
  const int sidx = (dir * BATCH + b) * HID + j;
  float c  = initFlag ? 0.f : cst[sidx];
  float hv = initFlag ? 0.f : hst[sidx];
  h_lds[j] = hv;
  __syncthreads();

  int t = dir ? tB0 : tF0;
  const int dt = dir ? -1 : 1;
  int lt = dir ? (TC - 1) : 0;

  float xi = xw[((size_t)lt * BATCH + b) * G4 + j];
  float xf = xw[((size_t)lt * BATCH + b) * G4 + HID + j];
  float xg = xw[((size_t)lt * BATCH + b) * G4 + 2 * HID + j];
  float xo = xw[((size_t)lt * BATCH + b) * G4 + 3 * HID + j];

  for (int it = 0; it < TC; ++it) {
    int ltn = dir ? (TC - 2 - it) : (it + 1);
    ltn = (ltn < 0) ? 0 : ((ltn > TC - 1) ? (TC - 1) : ltn);
    const float* nrow = xw + ((size_t)ltn * BATCH + b) * G4;
    const float nxi = nrow[j], nxf = nrow[HID + j], nxg = nrow[2 * HID + j], nxo = nrow[3 * HID + j];

    f32x2 aif0 = f32x2{xi, xf}, ago0 = f32x2{xg, xo};
    f32x2 aif1 = f32x2{0.f, 0.f}, ago1 = f32x2{0.f, 0.f};
    hh_pk(h_lds, w_if, w_go, aif0, aif1, ago0, ago1);
    const f32x2 pif = aif0 + aif1;
    const f32x2 pgo = ago0 + ago1;

    const float i_ = sig_(pif.x), f_ = sig_(pif.y);
    const float g_ = tanh_(pgo.x), o_ = sig_(pgo.y);
    c = fmaf(f_, c, i_ * g_);
    hv = o_ * tanh_(c);
    h_lds[j] = hv;
    stv(&seq[((size_t)t * BATCH + b) * D2 + dir * HID + j], hv);

    xi = nxi; xf = nxf; xg = nxg; xo = nxo;
    t += dt;
    lt = ltn;
  }
  hst[sidx] = hv;
  cst[sidx] = c;
}

// ---------------------------------------------------------------------------
// Layers 1/2 input GEMM over a row range.
// ---------------------------------------------------------------------------
template<typename ST>
__global__ __launch_bounds__(128) void k_gemm12(const ST* __restrict__ seq,
                                                const float* __restrict__ wih,
                                                const float* __restrict__ bih,
                                                const float* __restrict__ bhh,
                                                float* __restrict__ xw, int rowoff) {
  __shared__ float in_lds[64][64];
  __shared__ float w_lds[256][32];
  const int tid = threadIdx.x;
  const int cg = tid & 31;
  const int rg = tid >> 5;
  const size_t gr0 = (size_t)rowoff + (size_t)blockIdx.x * 64;
  const size_t lr0 = (size_t)blockIdx.x * 64;

  float acc[16][8];
#pragma unroll
  for (int rr = 0; rr < 16; ++rr)
#pragma unroll
    for (int j = 0; j < 8; ++j) acc[rr][j] = 0.f;

  for (int kh = 0; kh < 2; ++kh) {
    __syncthreads();
    if constexpr (__is_same(ST, float)) {
      float4* dst = reinterpret_cast<float4*>(&in_lds[0][0]);
      for (int e = tid; e < 64 * 16; e += 128) {
        int row = e >> 4, cf4 = e & 15;
        dst[e] = *reinterpret_cast<const float4*>(&seq[(gr0 + row) * D2 + kh * 64 + cf4 * 4]);
      }
    } else {
      float* dstf = &in_lds[0][0];
      const __half2* src = reinterpret_cast<const __half2*>(seq);
      for (int e = tid; e < 64 * 32; e += 128) {
        int row = e >> 5, ch2 = e & 31;
        float2 f = __half22float2(src[(gr0 + row) * (D2 / 2) + kh * 32 + ch2]);
        dstf[row * 64 + ch2 * 2]     = f.x;
        dstf[row * 64 + ch2 * 2 + 1] = f.y;
      }
    }
    for (int kc2 = 0; kc2 < 2; ++kc2) {
      __syncthreads();
      int k0 = kh * 64 + kc2 * 32;
      for (int e4 = tid * 4; e4 < 256 * 32; e4 += 128 * 4) {
        int cc = e4 >> 5, kk = e4 & 31;
        float4 v = *reinterpret_cast<const float4*>(&wih[(size_t)cc * D2 + k0 + kk]);
        *reinterpret_cast<float4*>(&w_lds[cc][kk ^ (((cc >> 3) & 7) << 2)]) = v;
      }
      __syncthreads();
#pragma unroll
      for (int k4 = 0; k4 < 8; ++k4) {
        float4 wv[8];
#pragma unroll
        for (int j = 0; j < 8; ++j)
          wv[j] = *reinterpret_cast<const float4*>(&w_lds[cg * 8 + j][(k4 * 4) ^ ((cg & 7) << 2)]);
#pragma unroll
        for (int rr = 0; rr < 16; ++rr) {
          float4 iv = *reinterpret_cast<const float4*>(&in_lds[rg * 16 + rr][kc2 * 32 + k4 * 4]);
#pragma unroll
          for (int j = 0; j < 8; ++j) {
            acc[rr][j] = fmaf(iv.x, wv[j].x, acc[rr][j]);
            acc[rr][j] = fmaf(iv.y, wv[j].y, acc[rr][j]);
            acc[rr][j] = fmaf(iv.z, wv[j].z, acc[rr][j]);
            acc[rr][j] = fmaf(iv.w, wv[j].w, acc[rr][j]);
          }
        }
      }
    }
  }
  float bb[8];
#pragma unroll
  for (int j = 0; j < 8; ++j) bb[j] = bih[cg * 8 + j] + bhh[cg * 8 + j];
#pragma unroll
  for (int rr = 0; rr < 16; ++rr) {
    float* orow = xw + (lr0 + rg * 16 + rr) * G4 + cg * 8;
    float4 o0 = { acc[rr][0] + bb[0], acc[rr][1] + bb[1], acc[rr][2] + bb[2], acc[rr][3] + bb[3] };
    float4 o1 = { acc[rr][4] + bb[4], acc[rr][5] + bb[5], acc[rr][6] + bb[6], acc[rr][7] + bb[7] };
    *reinterpret_cast<float4*>(orow) = o0;
    *reinterpret_cast<float4*>(orow + 4) = o1;
  }
}

// ---------------------------------------------------------------------------
// Head MLP.
// ---------------------------------------------------------------------------
template<typename ST>
__global__ __launch_bounds__(128) void k_head(const ST* __restrict__ seq,
                                              const float* __restrict__ Wc1, const float* __restrict__ bc1,
                                              const float* __restrict__ Wc2, const float* __restrict__ bc2,
                                              const float* __restrict__ Wc3, const float* __restrict__ bc3,
                                              float* __restrict__ out) {
  int b = blockIdx.x;
  int tid = threadIdx.x;
  __shared__ float fin[D2], z1[D2], z2[HID];
  if (tid < HID) fin[tid] = ldv(&seq[((size_t)(T_LEN - 1) * BATCH + b) * D2 + tid]);
  else           fin[tid] = ldv(&seq[(size_t)b * D2 + tid]);
  __syncthreads();
  float s = bc1[tid];
  for (int k = 0; k < D2; ++k) s = fmaf(fin[k], Wc1[(size_t)tid * D2 + k], s);
  z1[tid] = fmaxf(s, 0.f);
  __syncthreads();
  if (tid < HID) {
    float s2 = bc2[tid];
    for (int k = 0; k < D2; ++k) s2 = fmaf(z1[k], Wc2[(size_t)tid * D2 + k], s2);
    z2[tid] = fmaxf(s2, 0.f);
  }
  __syncthreads();
  if (tid < 20) {
    float s3 = bc3[tid];
    for (int k = 0; k < HID; ++k) s3 = fmaf(z2[k], Wc3[(size_t)tid * HID + k], s3);
    out[b * 20 + tid] = s3;
  }
}

// ---------------------------------------------------------------------------
template<typename ST>
static void run_all(const float* x, const float* Wp, const float* bp,
                    const float* w_ih0, const float* w_hh0, const float* b_ih0, const float* b_hh0,
                    const float* w_ih12, const float* w_hh12, const float* b_ih12, const float* b_hh12,
                    const float* Wc1, const float* bc1, const float* Wc2, const float* bc2,
                    const float* Wc3, const float* bc3,
                    float* out, char* ws, int TC, hipStream_t stream) {
  ST* seqA = (ST*)ws;
  ST* seqB = seqA + (size_t)NROW * D2;
  uintptr_t up = ((uintptr_t)(seqB + (size_t)NROW * D2) + 255) & ~(uintptr_t)255;
  float* xwF = (float*)up;
  float* xwB = xwF + (size_t)TC * BATCH * G4;
  float* hst = xwB + (size_t)TC * BATCH * G4;
  float* cst = hst + 2 * BATCH * HID;
  float* w0p = cst + 2 * BATCH * HID;
  float* b0p = w0p + 2 * G4 * CH;

  hipLaunchKernelGGL(k_prep0, dim3(2), dim3(256), 0, stream, Wp, bp, w_ih0, b_ih0, b_hh0, w0p, b0p);
  hipLaunchKernelGGL(k_recur0<ST>, dim3(128), dim3(64), 0, stream, x, w0p, b0p, w_hh0, seqA);

  int NC = T_LEN / TC;
  for (int l = 0; l < 2; ++l) {
    const float* wih0d = w_ih12 + (size_t)(l * 2) * G4 * D2;
    const float* wih1d = wih0d + (size_t)G4 * D2;
    const float* whh_l = w_hh12 + (size_t)(l * 2) * G4 * HID;
    const float* bi0 = b_ih12 + (size_t)(l * 2) * G4;
    const float* bh0 = b_hh12 + (size_t)(l * 2) * G4;
    ST* sin  = (l == 0) ? seqA : seqB;
    ST* sout = (l == 0) ? seqB : seqA;
    for (int c = 0; c < NC; ++c) {
      int cb = NC - 1 - c;
      hipLaunchKernelGGL(k_gemm12<ST>, dim3(TC), dim3(128), 0, stream,
                         sin, wih0d, bi0, bh0, xwF, c * TC * BATCH);
      hipLaunchKernelGGL(k_gemm12<ST>, dim3(TC), dim3(128), 0, stream,
                         sin, wih1d, bi0 + G4, bh0 + G4, xwB, cb * TC * BATCH);
      hipLaunchKernelGGL(k_recur12<ST>, dim3(128), dim3(64), 0, stream,
                         xwF, xwB, whh_l, sout, hst, cst, (c == 0) ? 1 : 0,
                         c * TC, cb * TC + TC - 1, TC);
    }
  }
  hipLaunchKernelGGL(k_head<ST>, dim3(BATCH), dim3(128), 0, stream,
                     seqA, Wc1, bc1, Wc2, bc2, Wc3, bc3, out);
}

extern "C" void kernel_launch(void* const* d_in, const int* in_sizes, int n_in,
                              void* d_out, int out_size, void* d_ws, size_t ws_size,
                              hipStream_t stream) {
  const float* x      = (const float*)d_in[0];
  const float* Wp     = (const float*)d_in[1];
  const float* bp     = (const float*)d_in[2];
  const float* w_ih0  = (const float*)d_in[3];
  const float* w_hh0  = (const float*)d_in[4];
  const float* b_ih0  = (const float*)d_in[5];
  const float* b_hh0  = (const float*)d_in[6];
  const float* w_ih12 = (const float*)d_in[7];
  const float* w_hh12 = (const float*)d_in[8];
  const float* b_ih12 = (const float*)d_in[9];
  const float* b_hh12 = (const float*)d_in[10];
  const float* Wc1    = (const float*)d_in[11];
  const float* bc1    = (const float*)d_in[12];
  const float* Wc2    = (const float*)d_in[13];
  const float* bc2    = (const float*)d_in[14];
  const float* Wc3    = (const float*)d_in[15];
  const float* bc3    = (const float*)d_in[16];
  float* out = (float*)d_out;
  char* ws = (char*)d_ws;

  auto need = [](bool half, int TC) -> size_t {
    size_t seqb  = (size_t)NROW * D2 * (half ? 2 : 4) * 2;
    size_t chunk = (size_t)2 * TC * BATCH * G4 * 4;
    size_t small = (size_t)(2 * 2 * BATCH * HID + 2 * G4 * CH + 2 * G4) * 4;
    return seqb + chunk + small + 1024;
  };

  struct Opt { bool h; int tc; };
  const Opt opts[] = { {false,625},{false,500},{false,250},{false,125},{false,100},
                       {true,625},{true,500},{true,250},{true,125},{true,100},{true,50},{true,25} };
  bool useHalf = true; int TC = 25;
  for (const Opt& o : opts) {
    if (need(o.h, o.tc) <= ws_size) { useHalf = o.h; TC = o.tc; break; }
  }

  if (!useHalf)
    run_all<float>(x, Wp, bp, w_ih0, w_hh0, b_ih0, b_hh0, w_ih12, w_hh12, b_ih12, b_hh12,
                   Wc1, bc1, Wc2, bc2, Wc3, bc3, out, ws, TC, stream);
  else
    run_all<__half>(x, Wp, bp, w_ih0, w_hh0, b_ih0, b_hh0, w_ih12, w_hh12, b_ih12, b_hh12,
                    Wc1, bc1, Wc2, bc2, Wc3, bc3, out, ws, TC, stream);
}

// Round 5
// 5978.573 us; speedup vs baseline: 1.6388x; 1.6388x over previous
//
#include <hip/hip_runtime.h>
#include <hip/hip_fp16.h>
#include <math.h>

#define T_LEN 2500
#define BATCH 64
#define CH    12
#define HID   64
#define G4    256   // 4*H
#define D2    128   // 2*H
#define NROW  (T_LEN*BATCH)

__device__ __forceinline__ float rcp_(float x){ return __builtin_amdgcn_rcpf(x); }
__device__ __forceinline__ float sig_(float x){ return rcp_(1.f + __expf(-x)); }

__device__ __forceinline__ float ldv(const float* p){ return *p; }
__device__ __forceinline__ float ldv(const __half* p){ return __half2float(*p); }
__device__ __forceinline__ void stv(float* p, float v){ *p = v; }
__device__ __forceinline__ void stv(__half* p, float v){ *p = __float2half(v); }

// quad_perm DPP move (full-rate VALU)
template<int CTRL>
__device__ __forceinline__ float qperm(float v) {
  return __int_as_float(__builtin_amdgcn_mov_dpp(__float_as_int(v), CTRL, 0xf, 0xf, true));
}

// Raw barrier: LDS-ordering only; does NOT drain vmcnt (global prefetch stays in flight).
__device__ __forceinline__ void bar_lds() {
  asm volatile("s_waitcnt lgkmcnt(0)" ::: "memory");
  __builtin_amdgcn_s_barrier();
  __builtin_amdgcn_sched_barrier(0);
}

// dot over K=64 from LDS-broadcast h, 4 independent chains.
__device__ __forceinline__ float dot64(const float* hr, const float* w, float seed) {
  float s0 = seed, s1 = 0.f, s2 = 0.f, s3 = 0.f;
#pragma unroll
  for (int k = 0; k < HID; k += 16) {
    const float4 a0 = *reinterpret_cast<const float4*>(&hr[k]);
    const float4 a1 = *reinterpret_cast<const float4*>(&hr[k + 4]);
    const float4 a2 = *reinterpret_cast<const float4*>(&hr[k + 8]);
    const float4 a3 = *reinterpret_cast<const float4*>(&hr[k + 12]);
    s0 = fmaf(a0.x, w[k], s0);      s0 = fmaf(a0.y, w[k + 1], s0);
    s0 = fmaf(a0.z, w[k + 2], s0);  s0 = fmaf(a0.w, w[k + 3], s0);
    s1 = fmaf(a1.x, w[k + 4], s1);  s1 = fmaf(a1.y, w[k + 5], s1);
    s1 = fmaf(a1.z, w[k + 6], s1);  s1 = fmaf(a1.w, w[k + 7], s1);
    s2 = fmaf(a2.x, w[k + 8], s2);  s2 = fmaf(a2.y, w[k + 9], s2);
    s2 = fmaf(a2.z, w[k + 10], s2); s2 = fmaf(a2.w, w[k + 11], s2);
    s3 = fmaf(a3.x, w[k + 12], s3); s3 = fmaf(a3.y, w[k + 13], s3);
    s3 = fmaf(a3.z, w[k + 14], s3); s3 = fmaf(a3.w, w[k + 15], s3);
  }
  return (s0 + s1) + (s2 + s3);
}

// Per-lane gate nonlinearity (gi==2 -> tanh, else sigmoid), then quad-gather
// into leader (gi==0) and cell update. All lanes compute; only leader's valid.
__device__ __forceinline__ float cell_update(float v, int gi, float& c) {
  const float z = (gi == 2) ? (v + v) : v;
  const float y = sig_(z);
  const float act = (gi == 2) ? fmaf(2.f, y, -1.f) : y;
  const float t1 = qperm<0xB1>(act);   // lane^1
  const float t2 = qperm<0x4E>(act);   // lane^2
  const float t3 = qperm<0x4E>(t1);    // lane^3
  // leader: act=i, t1=f, t2=g, t3=o
  c = fmaf(t1, c, act * t2);
  const float y2 = sig_(c + c);
  const float th = fmaf(2.f, y2, -1.f);   // tanh(c)
  return t3 * th;
}

// ---------------------------------------------------------------------------
// Fold input projection into layer-0 input weights.
// ---------------------------------------------------------------------------
__global__ void k_prep0(const float* __restrict__ Wp, const float* __restrict__ bp,
                        const float* __restrict__ w_ih0,
                        const float* __restrict__ b_ih0, const float* __restrict__ b_hh0,
                        float* __restrict__ w0p, float* __restrict__ b0p) {
  int tid = blockIdx.x * blockDim.x + threadIdx.x;
  if (tid >= 2 * G4) return;
  const float* wih = w_ih0 + (size_t)tid * HID;
  float bb = b_ih0[tid] + b_hh0[tid];
  for (int j = 0; j < HID; ++j) bb += wih[j] * bp[j];
  b0p[tid] = bb;
  for (int c = 0; c < CH; ++c) {
    float s = 0.f;
    for (int j = 0; j < HID; ++j) s += wih[j] * Wp[j * CH + c];
    w0p[(size_t)tid * CH + c] = s;
  }
}

// ---------------------------------------------------------------------------
// Layer-0 recurrence. WG per (dir,b), 256 thr = 4 waves.
// lane -> (unit j = w*16 + l/4, gate gi = l&3); 64 weight VGPRs per lane.
// One raw barrier per step; h double-buffered in LDS.
// ---------------------------------------------------------------------------
template<typename ST>
__global__ __launch_bounds__(256) void k_recur0(const float* __restrict__ x,
                                                const float* __restrict__ w0p,
                                                const float* __restrict__ b0p,
                                                const float* __restrict__ whh,
                                                ST* __restrict__ seq) {
  const int wg = blockIdx.x, dir = wg >> 6, b = wg & 63;
  const int w4 = threadIdx.x >> 6, l = threadIdx.x & 63;
  const int gi = l & 3, j = w4 * 16 + (l >> 2);
  const int row = dir * G4 + gi * HID + j;

  float w[HID];
  {
    const float* W = whh + (size_t)row * HID;
#pragma unroll
    for (int k = 0; k < HID; ++k) w[k] = W[k];
  }
  float w0[CH];
  {
    const float* P = w0p + (size_t)row * CH;
#pragma unroll
    for (int c = 0; c < CH; ++c) w0[c] = P[c];
  }
  const float bb = b0p[row];

  __shared__ __align__(16) float h_lds[2][HID];
  if (threadIdx.x < HID) { h_lds[0][threadIdx.x] = 0.f; }
  float c = 0.f;

  int t = dir ? (T_LEN - 1) : 0;
  const int dt = dir ? -1 : 1;
  const float* xb = x + (size_t)b * CH * T_LEN;

  float xc[CH], xn[CH];
#pragma unroll
  for (int cc = 0; cc < CH; ++cc) xc[cc] = xb[(size_t)cc * T_LEN + t];
  {
    const int t1 = t + dt;
#pragma unroll
    for (int cc = 0; cc < CH; ++cc) xn[cc] = xb[(size_t)cc * T_LEN + t1];
  }
  bar_lds();

  int par = 0;
#pragma unroll 2
  for (int it = 0; it < T_LEN; ++it) {
    // seed = bias + input projection (uses xc = x[t])
    float p0 = bb, p1 = 0.f, p2 = 0.f;
#pragma unroll
    for (int cc = 0; cc < 4; ++cc)  p0 = fmaf(xc[cc], w0[cc], p0);
#pragma unroll
    for (int cc = 4; cc < 8; ++cc)  p1 = fmaf(xc[cc], w0[cc], p1);
#pragma unroll
    for (int cc = 8; cc < 12; ++cc) p2 = fmaf(xc[cc], w0[cc], p2);

    // shift prefetch and issue loads for t+2 (overlaps the dot below)
#pragma unroll
    for (int cc = 0; cc < CH; ++cc) xc[cc] = xn[cc];
    {
      int t2 = t + 2 * dt;
      t2 = (t2 < 0) ? 0 : ((t2 > T_LEN - 1) ? (T_LEN - 1) : t2);
#pragma unroll
      for (int cc = 0; cc < CH; ++cc) xn[cc] = xb[(size_t)cc * T_LEN + t2];
    }

    const float pre = dot64(&h_lds[par][0], w, (p0 + p1) + p2);
    const float hv = cell_update(pre, gi, c);

    if ((l & 3) == 0) {
      h_lds[par ^ 1][j] = hv;
      stv(&seq[((size_t)t * BATCH + b) * D2 + dir * HID + j], hv);
    }
    bar_lds();
    par ^= 1;
    t += dt;
  }
}

// ---------------------------------------------------------------------------
// Layers 1/2 recurrence over one time-chunk; 1 xw float per lane per step,
// prefetched 3 deep; h/c carried across chunks.
// ---------------------------------------------------------------------------
template<typename ST>
__global__ __launch_bounds__(256) void k_recur12(const float* __restrict__ xwF,
                                                 const float* __restrict__ xwB,
                                                 const float* __restrict__ whh,
                                                 ST* __restrict__ seq,
                                                 float* __restrict__ hst, float* __restrict__ cst,
                                                 int initFlag, int tF0, int tB0, int TC) {
  const int wg = blockIdx.x, dir = wg >> 6, b = wg & 63;
  const int w4 = threadIdx.x >> 6, l = threadIdx.x & 63;
  const int gi = l & 3, j = w4 * 16 + (l >> 2);
  const float* xw = dir ? xwB : xwF;

  float w[HID];
  {
    const float* W = whh + ((size_t)dir * G4 + gi * HID + j) * HID;
#pragma unroll
    for (int k = 0; k < HID; ++k) w[k] = W[k];
  }

  __shared__ __align__(16) float h_lds[2][HID];
  const int sidx = (dir * BATCH + b) * HID + j;
  float c = 0.f;
  if (threadIdx.x < HID) {
    h_lds[0][threadIdx.x] = initFlag ? 0.f
        : hst[(dir * BATCH + b) * HID + threadIdx.x];
  }
  if ((l & 3) == 0 && !initFlag) c = cst[sidx];

  // lane's xw element within a row: gi*64 + j
  const int goff = gi * HID + j;
  auto ltAt = [&](int i) { int ii = (i > TC - 1) ? (TC - 1) : i; return dir ? (TC - 1 - ii) : ii; };
  float xcur = xw[((size_t)ltAt(0) * BATCH + b) * G4 + goff];
  float xn1  = xw[((size_t)ltAt(1) * BATCH + b) * G4 + goff];
  float xn2  = xw[((size_t)ltAt(2) * BATCH + b) * G4 + goff];

  int t = dir ? tB0 : tF0;
  const int dt = dir ? -1 : 1;
  bar_lds();

  int par = 0;
#pragma unroll 2
  for (int it = 0; it < TC; ++it) {
    const float xn3 = xw[((size_t)ltAt(it + 3) * BATCH + b) * G4 + goff];

    const float pre = dot64(&h_lds[par][0], w, xcur);
    const float hv = cell_update(pre, gi, c);

    if ((l & 3) == 0) {
      h_lds[par ^ 1][j] = hv;
      stv(&seq[((size_t)t * BATCH + b) * D2 + dir * HID + j], hv);
    }
    bar_lds();
    par ^= 1;
    xcur = xn1; xn1 = xn2; xn2 = xn3;
    t += dt;
  }
  if ((l & 3) == 0) {
    hst[sidx] = h_lds[par][j];
    cst[sidx] = c;
  }
}

// ---------------------------------------------------------------------------
// Layers 1/2 input GEMM over a row range (unchanged).
// ---------------------------------------------------------------------------
template<typename ST>
__global__ __launch_bounds__(128) void k_gemm12(const ST* __restrict__ seq,
                                                const float* __restrict__ wih,
                                                const float* __restrict__ bih,
                                                const float* __restrict__ bhh,
                                                float* __restrict__ xw, int rowoff) {
  __shared__ float in_lds[64][64];
  __shared__ float w_lds[256][32];
  const int tid = threadIdx.x;
  const int cg = tid & 31;
  const int rg = tid >> 5;
  const size_t gr0 = (size_t)rowoff + (size_t)blockIdx.x * 64;
  const size_t lr0 = (size_t)blockIdx.x * 64;

  float acc[16][8];
#pragma unroll
  for (int rr = 0; rr < 16; ++rr)
#pragma unroll
    for (int j = 0; j < 8; ++j) acc[rr][j] = 0.f;

  for (int kh = 0; kh < 2; ++kh) {
    __syncthreads();
    if constexpr (__is_same(ST, float)) {
      float4* dst = reinterpret_cast<float4*>(&in_lds[0][0]);
      for (int e = tid; e < 64 * 16; e += 128) {
        int row = e >> 4, cf4 = e & 15;
        dst[e] = *reinterpret_cast<const float4*>(&seq[(gr0 + row) * D2 + kh * 64 + cf4 * 4]);
      }
    } else {
      float* dstf = &in_lds[0][0];
      const __half2* src = reinterpret_cast<const __half2*>(seq);
      for (int e = tid; e < 64 * 32; e += 128) {
        int row = e >> 5, ch2 = e & 31;
        float2 f = __half22float2(src[(gr0 + row) * (D2 / 2) + kh * 32 + ch2]);
        dstf[row * 64 + ch2 * 2]     = f.x;
        dstf[row * 64 + ch2 * 2 + 1] = f.y;
      }
    }
    for (int kc2 = 0; kc2 < 2; ++kc2) {
      __syncthreads();
      int k0 = kh * 64 + kc2 * 32;
      for (int e4 = tid * 4; e4 < 256 * 32; e4 += 128 * 4) {
        int cc = e4 >> 5, kk = e4 & 31;
        float4 v = *reinterpret_cast<const float4*>(&wih[(size_t)cc * D2 + k0 + kk]);
        *reinterpret_cast<float4*>(&w_lds[cc][kk ^ (((cc >> 3) & 7) << 2)]) = v;
      }
      __syncthreads();
#pragma unroll
      for (int k4 = 0; k4 < 8; ++k4) {
        float4 wv[8];
#pragma unroll
        for (int j = 0; j < 8; ++j)
          wv[j] = *reinterpret_cast<const float4*>(&w_lds[cg * 8 + j][(k4 * 4) ^ ((cg & 7) << 2)]);
#pragma unroll
        for (int rr = 0; rr < 16; ++rr) {
          float4 iv = *reinterpret_cast<const float4*>(&in_lds[rg * 16 + rr][kc2 * 32 + k4 * 4]);
#pragma unroll
          for (int j = 0; j < 8; ++j) {
            acc[rr][j] = fmaf(iv.x, wv[j].x, acc[rr][j]);
            acc[rr][j] = fmaf(iv.y, wv[j].y, acc[rr][j]);
            acc[rr][j] = fmaf(iv.z, wv[j].z, acc[rr][j]);
            acc[rr][j] = fmaf(iv.w, wv[j].w, acc[rr][j]);
          }
        }
      }
    }
  }
  float bb[8];
#pragma unroll
  for (int j = 0; j < 8; ++j) bb[j] = bih[cg * 8 + j] + bhh[cg * 8 + j];
#pragma unroll
  for (int rr = 0; rr < 16; ++rr) {
    float* orow = xw + (lr0 + rg * 16 + rr) * G4 + cg * 8;
    float4 o0 = { acc[rr][0] + bb[0], acc[rr][1] + bb[1], acc[rr][2] + bb[2], acc[rr][3] + bb[3] };
    float4 o1 = { acc[rr][4] + bb[4], acc[rr][5] + bb[5], acc[rr][6] + bb[6], acc[rr][7] + bb[7] };
    *reinterpret_cast<float4*>(orow) = o0;
    *reinterpret_cast<float4*>(orow + 4) = o1;
  }
}

// ---------------------------------------------------------------------------
// Head MLP.
// ---------------------------------------------------------------------------
template<typename ST>
__global__ __launch_bounds__(128) void k_head(const ST* __restrict__ seq,
                                              const float* __restrict__ Wc1, const float* __restrict__ bc1,
                                              const float* __restrict__ Wc2, const float* __restrict__ bc2,
                                              const float* __restrict__ Wc3, const float* __restrict__ bc3,
                                              float* __restrict__ out) {
  int b = blockIdx.x;
  int tid = threadIdx.x;
  __shared__ float fin[D2], z1[D2], z2[HID];
  if (tid < HID) fin[tid] = ldv(&seq[((size_t)(T_LEN - 1) * BATCH + b) * D2 + tid]);
  else           fin[tid] = ldv(&seq[(size_t)b * D2 + tid]);
  __syncthreads();
  float s = bc1[tid];
  for (int k = 0; k < D2; ++k) s = fmaf(fin[k], Wc1[(size_t)tid * D2 + k], s);
  z1[tid] = fmaxf(s, 0.f);
  __syncthreads();
  if (tid < HID) {
    float s2 = bc2[tid];
    for (int k = 0; k < D2; ++k) s2 = fmaf(z1[k], Wc2[(size_t)tid * D2 + k], s2);
    z2[tid] = fmaxf(s2, 0.f);
  }
  __syncthreads();
  if (tid < 20) {
    float s3 = bc3[tid];
    for (int k = 0; k < HID; ++k) s3 = fmaf(z2[k], Wc3[(size_t)tid * HID + k], s3);
    out[b * 20 + tid] = s3;
  }
}

// ---------------------------------------------------------------------------
template<typename ST>
static void run_all(const float* x, const float* Wp, const float* bp,
                    const float* w_ih0, const float* w_hh0, const float* b_ih0, const float* b_hh0,
                    const float* w_ih12, const float* w_hh12, const float* b_ih12, const float* b_hh12,
                    const float* Wc1, const float* bc1, const float* Wc2, const float* bc2,
                    const float* Wc3, const float* bc3,
                    float* out, char* ws, int TC, hipStream_t stream) {
  ST* seqA = (ST*)ws;
  ST* seqB = seqA + (size_t)NROW * D2;
  uintptr_t up = ((uintptr_t)(seqB + (size_t)NROW * D2) + 255) & ~(uintptr_t)255;
  float* xwF = (float*)up;
  float* xwB = xwF + (size_t)TC * BATCH * G4;
  float* hst = xwB + (size_t)TC * BATCH * G4;
  float* cst = hst + 2 * BATCH * HID;
  float* w0p = cst + 2 * BATCH * HID;
  float* b0p = w0p + 2 * G4 * CH;

  hipLaunchKernelGGL(k_prep0, dim3(2), dim3(256), 0, stream, Wp, bp, w_ih0, b_ih0, b_hh0, w0p, b0p);
  hipLaunchKernelGGL(k_recur0<ST>, dim3(128), dim3(256), 0, stream, x, w0p, b0p, w_hh0, seqA);

  int NC = T_LEN / TC;
  for (int l = 0; l < 2; ++l) {
    const float* wih0d = w_ih12 + (size_t)(l * 2) * G4 * D2;
    const float* wih1d = wih0d + (size_t)G4 * D2;
    const float* whh_l = w_hh12 + (size_t)(l * 2) * G4 * HID;
    const float* bi0 = b_ih12 + (size_t)(l * 2) * G4;
    const float* bh0 = b_hh12 + (size_t)(l * 2) * G4;
    ST* sin  = (l == 0) ? seqA : seqB;
    ST* sout = (l == 0) ? seqB : seqA;
    for (int c = 0; c < NC; ++c) {
      int cb = NC - 1 - c;
      hipLaunchKernelGGL(k_gemm12<ST>, dim3(TC), dim3(128), 0, stream,
                         sin, wih0d, bi0, bh0, xwF, c * TC * BATCH);
      hipLaunchKernelGGL(k_gemm12<ST>, dim3(TC), dim3(128), 0, stream,
                         sin, wih1d, bi0 + G4, bh0 + G4, xwB, cb * TC * BATCH);
      hipLaunchKernelGGL(k_recur12<ST>, dim3(128), dim3(256), 0, stream,
                         xwF, xwB, whh_l, sout, hst, cst, (c == 0) ? 1 : 0,
                         c * TC, cb * TC + TC - 1, TC);
    }
  }
  hipLaunchKernelGGL(k_head<ST>, dim3(BATCH), dim3(128), 0, stream,
                     seqA, Wc1, bc1, Wc2, bc2, Wc3, bc3, out);
}

extern "C" void kernel_launch(void* const* d_in, const int* in_sizes, int n_in,
                              void* d_out, int out_size, void* d_ws, size_t ws_size,
                              hipStream_t stream) {
  const float* x      = (const float*)d_in[0];
  const float* Wp     = (const float*)d_in[1];
  const float* bp     = (const float*)d_in[2];
  const float* w_ih0  = (const float*)d_in[3];
  const float* w_hh0  = (const float*)d_in[4];
  const float* b_ih0  = (const float*)d_in[5];
  const float* b_hh0  = (const float*)d_in[6];
  const float* w_ih12 = (const float*)d_in[7];
  const float* w_hh12 = (const float*)d_in[8];
  const float* b_ih12 = (const float*)d_in[9];
  const float* b_hh12 = (const float*)d_in[10];
  const float* Wc1    = (const float*)d_in[11];
  const float* bc1    = (const float*)d_in[12];
  const float* Wc2    = (const float*)d_in[13];
  const float* bc2    = (const float*)d_in[14];
  const float* Wc3    = (const float*)d_in[15];
  const float* bc3    = (const float*)d_in[16];
  float* out = (float*)d_out;
  char* ws = (char*)d_ws;

  auto need = [](bool half, int TC) -> size_t {
    size_t seqb  = (size_t)NROW * D2 * (half ? 2 : 4) * 2;
    size_t chunk = (size_t)2 * TC * BATCH * G4 * 4;
    size_t small = (size_t)(2 * 2 * BATCH * HID + 2 * G4 * CH + 2 * G4) * 4;
    return seqb + chunk + small + 1024;
  };

  struct Opt { bool h; int tc; };
  const Opt opts[] = { {false,625},{false,500},{false,250},{false,125},{false,100},
                       {true,625},{true,500},{true,250},{true,125},{true,100},{true,50},{true,25} };
  bool useHalf = true; int TC = 25;
  for (const Opt& o : opts) {
    if (need(o.h, o.tc) <= ws_size) { useHalf = o.h; TC = o.tc; break; }
  }

  if (!useHalf)
    run_all<float>(x, Wp, bp, w_ih0, w_hh0, b_ih0, b_hh0, w_ih12, w_hh12, b_ih12, b_hh12,
                   Wc1, bc1, Wc2, bc2, Wc3, bc3, out, ws, TC, stream);
  else
    run_all<__half>(x, Wp, bp, w_ih0, w_hh0, b_ih0, b_hh0, w_ih12, w_hh12, b_ih12, b_hh12,
                    Wc1, bc1, Wc2, bc2, Wc3, bc3, out, ws, TC, stream);
}